// Round 15
// baseline (100.047 us; speedup 1.0000x reference)
//
#include <hip/hip_runtime.h>
#include <stdint.h>

typedef float f32x16 __attribute__((ext_vector_type(16)));
typedef long long2v __attribute__((ext_vector_type(2)));

#define BDIM 8192
// fp8 matrices stored paired-16B k-major: for byte (row, k):
//   fh = (k>>3)&1, s = k>>4 (0..7), p = s>>1, o = s&1, j = k&7
//   addr = fh*524288 + p*131072 + row*16 + o*8 + j        (1 MB per matrix)
// MFMA operands for steps s=2p and s=2p+1 (half fh, row) = one 16-B run at
// fh*524288 + p*131072 + row*16 -> one coalesced global_load_dwordx4 per lane.

// fp32 [8192,128] -> fp8 e4m3 paired-16B layout + fp32 row sum-of-squares.
// grid (512, 2): 16 rows/block. jg = lane&15 handles k = 8jg..8jg+7.
__global__ __launch_bounds__(256) void prep_kernel(const float* __restrict__ out_f,
                                                   const float* __restrict__ tgt_f,
                                                   uint8_t* __restrict__ ak,
                                                   float* __restrict__ xxyy) {
    const float* src = blockIdx.y ? tgt_f : out_f;
    uint8_t* dst = ak + (size_t)blockIdx.y * (1u << 20);
    float* nrm = xxyy + (size_t)blockIdx.y * BDIM;

    const int tid = threadIdx.x;
    const int lane = tid & 63;
    const int w = tid >> 6;
    const int jg = lane & 15;
    const int r = blockIdx.x * 16 + w * 4 + (lane >> 4);

    const float4* s4 = (const float4*)(src + (size_t)r * 128 + jg * 8);
    float4 a = s4[0], b = s4[1];

    uint32_t w0 = __builtin_amdgcn_cvt_pk_fp8_f32(a.x, a.y, 0, false);
    w0 = __builtin_amdgcn_cvt_pk_fp8_f32(a.z, a.w, w0, true);
    uint32_t w1 = __builtin_amdgcn_cvt_pk_fp8_f32(b.x, b.y, 0, false);
    w1 = __builtin_amdgcn_cvt_pk_fp8_f32(b.z, b.w, w1, true);

    // k-range 8jg..8jg+7: fh = jg&1, p = jg>>2, o = (jg>>1)&1.
    *(uint2*)(dst + (jg & 1) * 524288 + (jg >> 2) * 131072
                  + r * 16 + ((jg >> 1) & 1) * 8) = make_uint2(w0, w1);

    float sq = a.x*a.x + a.y*a.y + a.z*a.z + a.w*a.w
             + b.x*b.x + b.y*b.y + b.z*b.z + b.w*b.w;
    sq += __shfl_xor(sq, 1); sq += __shfl_xor(sq, 2);
    sq += __shfl_xor(sq, 4); sq += __shfl_xor(sq, 8);
    if (jg == 0) nrm[r] = sq;
}

// 4 serial 128x128 tiles per block, fixed bx (grid 64 x 16), j-loop NOT
// unrolled so exactly one tile's acc/load lifetime exists at a time (the
// R7/R13 spill came from unrolling this loop). A-operand addresses repeat
// across j -> L1-hot after tile 0; L2 staging traffic drops 268 -> ~100 MB.
// Operands direct-from-global as coalesced dwordx4. yy read per tile from
// global (L2-hot, 2 scalars/thread); xx via LDS once.
__global__ __launch_bounds__(256, 4) void dist_kernel(const uint8_t* __restrict__ Ak,
                                                      const uint8_t* __restrict__ Bk,
                                                      const float* __restrict__ xxg,
                                                      const float* __restrict__ yyg,
                                                      float* __restrict__ partials) {
    __shared__ float xxl[128];
    __shared__ float wsum[4];

    const int tid = threadIdx.x;
    const int lane = tid & 63;
    const int wid = tid >> 6;
    const int wr = wid >> 1, wc = wid & 1;      // 2x2 wave grid, each wave 64x64
    const int bx = blockIdx.x;
    const int byg = blockIdx.y;                 // tiles (bx, 4*byg + j)

    if (tid < 128) xxl[tid] = xxg[bx * 128 + tid];
    __syncthreads();

    const int lm = lane & 31;
    const int fh = lane >> 5;
    const uint8_t* pa = Ak + fh * 524288 + (size_t)(bx * 128 + wr * 64 + lm) * 16;

    float s0 = 0.0f, s1 = 0.0f;

    #pragma unroll 1
    for (int j = 0; j < 4; ++j) {
        const int by = byg * 4 + j;
        const uint8_t* pb = Bk + fh * 524288 + (size_t)(by * 128 + wc * 64 + lm) * 16;

        f32x16 acc[2][2] = {};
        #pragma unroll
        for (int p = 0; p < 4; ++p) {           // each p covers steps 2p, 2p+1
            long2v a0 = *(const long2v*)(pa + p * 131072);
            long2v a1 = *(const long2v*)(pa + p * 131072 + 512);   // +32 rows
            long2v b0 = *(const long2v*)(pb + p * 131072);
            long2v b1 = *(const long2v*)(pb + p * 131072 + 512);
            #pragma unroll
            for (int e = 0; e < 2; ++e) {
                acc[0][0] = __builtin_amdgcn_mfma_f32_32x32x16_fp8_fp8(a0[e], b0[e], acc[0][0], 0, 0, 0);
                acc[0][1] = __builtin_amdgcn_mfma_f32_32x32x16_fp8_fp8(a0[e], b1[e], acc[0][1], 0, 0, 0);
                acc[1][0] = __builtin_amdgcn_mfma_f32_32x32x16_fp8_fp8(a1[e], b0[e], acc[1][0], 0, 0, 0);
                acc[1][1] = __builtin_amdgcn_mfma_f32_32x32x16_fp8_fp8(a1[e], b1[e], acc[1][1], 0, 0, 0);
            }
        }

        const float yv0 = yyg[by * 128 + wc * 64 + lm];        // tc=0
        const float yv1 = yyg[by * 128 + wc * 64 + 32 + lm];   // tc=1

        // Epilogue: s += sqrt(|xx+yy-2c|) (d2 ~ [150,400]; abs is a free
        // input modifier on v_sqrt). 2-way split accumulator chains.
        #pragma unroll
        for (int tr = 0; tr < 2; ++tr) {
            float xv[16];
            #pragma unroll
            for (int r = 0; r < 16; ++r) {
                int ml = wr * 64 + tr * 32 + (r & 3) + 8 * (r >> 2) + 4 * fh;
                xv[r] = xxl[ml];
            }
            #pragma unroll
            for (int tc = 0; tc < 2; ++tc) {
                float yv = tc ? yv1 : yv0;
                #pragma unroll
                for (int r = 0; r < 16; ++r) {
                    float d2 = fmaf(-2.0f, acc[tr][tc][r], xv[r] + yv);
                    float d = __builtin_amdgcn_sqrtf(__builtin_fabsf(d2));
                    if (r & 1) s1 += d; else s0 += d;
                }
            }
        }

        // Diagonal correction: only blocks with bx == by, waves wr == wc.
        if (bx == by && wr == wc) {
            #pragma unroll
            for (int t = 0; t < 2; ++t) {
                #pragma unroll
                for (int r = 0; r < 16; ++r) {
                    int row = (r & 3) + 8 * (r >> 2) + 4 * fh;
                    if (row == lm) {
                        int idx = wr * 64 + t * 32 + row;
                        float d2 = fmaf(-2.0f, acc[t][t][r],
                                        xxl[idx] + yyg[by * 128 + idx]);
                        s0 -= 2.0f * __builtin_amdgcn_sqrtf(__builtin_fabsf(d2));
                    }
                }
            }
        }
    }

    float s = s0 + s1;
    #pragma unroll
    for (int off = 32; off > 0; off >>= 1) s += __shfl_down(s, off);
    if (lane == 0) wsum[wid] = s;
    __syncthreads();
    if (tid == 0) partials[byg * 64 + bx] = wsum[0] + wsum[1] + wsum[2] + wsum[3];
}

__global__ __launch_bounds__(256) void reduce_kernel(const float* __restrict__ partials,
                                                     float* __restrict__ out) {
    __shared__ float wsum[4];
    float s = 0.0f;
    #pragma unroll
    for (int i = 0; i < 4; ++i) s += partials[threadIdx.x + i * 256];
    #pragma unroll
    for (int off = 32; off > 0; off >>= 1) s += __shfl_down(s, off);
    int lane = threadIdx.x & 63, wid = threadIdx.x >> 6;
    if (lane == 0) wsum[wid] = s;
    __syncthreads();
    if (threadIdx.x == 0)
        out[0] = (wsum[0] + wsum[1] + wsum[2] + wsum[3]) * (0.1f / 8192.0f);
}

extern "C" void kernel_launch(void* const* d_in, const int* in_sizes, int n_in,
                              void* d_out, int out_size, void* d_ws, size_t ws_size,
                              hipStream_t stream) {
    const float* output = (const float*)d_in[0];
    const float* target = (const float*)d_in[1];

    uint8_t* ws = (uint8_t*)d_ws;
    uint8_t* ak      = ws;                                      // A fp8 (1MB) + B fp8 (1MB)
    float*   xxyy    = (float*)(ws + (2u << 20));               // xx (32KB) + yy (32KB)
    float*   partial = (float*)(ws + (2u << 20) + (64u << 10)); // 1024 f32

    prep_kernel<<<dim3(512, 2), 256, 0, stream>>>(output, target, ak, xxyy);
    dist_kernel<<<dim3(64, 16), 256, 0, stream>>>(ak, ak + (1u << 20),
                                                  xxyy, xxyy + BDIM, partial);
    reduce_kernel<<<1, 256, 0, stream>>>(partial, (float*)d_out);
}

// Round 16
// 77.084 us; speedup vs baseline: 1.2979x; 1.2979x over previous
//
#include <hip/hip_runtime.h>
#include <stdint.h>

typedef float f32x16 __attribute__((ext_vector_type(16)));
typedef int v8i __attribute__((ext_vector_type(8)));

#define BDIM 8192
// fp8 matrices stored 32B-run k-major for the K=64 scaled MFMA:
//   for byte (row, k): S = k>>6 (MFMA step), h = (k>>5)&1 (lane k-half),
//   addr = S*524288 + h*262144 + row*32 + (k&31)          (1 MB per matrix)
// Operand for (step S, half h, row): 32 contiguous bytes -> v8i load
// (2x global_load_dwordx4), consecutive lanes = consecutive 32 B (coalesced).
// A and B share this layout, so any consistent per-lane k-permutation inside
// the fragment cancels in A.B^T; scales are uniform 1.0 (E8M0 0x7F).

// fp32 [8192,128] -> fp8 e4m3 (32B-run layout) + fp32 row sum-of-squares.
// grid (512, 2): 16 rows/block. jg = lane&15 handles k = 8jg..8jg+7.
__global__ __launch_bounds__(256) void prep_kernel(const float* __restrict__ out_f,
                                                   const float* __restrict__ tgt_f,
                                                   uint8_t* __restrict__ ak,
                                                   float* __restrict__ xxyy) {
    const float* src = blockIdx.y ? tgt_f : out_f;
    uint8_t* dst = ak + (size_t)blockIdx.y * (1u << 20);
    float* nrm = xxyy + (size_t)blockIdx.y * BDIM;

    const int tid = threadIdx.x;
    const int lane = tid & 63;
    const int w = tid >> 6;
    const int jg = lane & 15;
    const int r = blockIdx.x * 16 + w * 4 + (lane >> 4);

    const float4* s4 = (const float4*)(src + (size_t)r * 128 + jg * 8);
    float4 a = s4[0], b = s4[1];

    uint32_t w0 = __builtin_amdgcn_cvt_pk_fp8_f32(a.x, a.y, 0, false);
    w0 = __builtin_amdgcn_cvt_pk_fp8_f32(a.z, a.w, w0, true);
    uint32_t w1 = __builtin_amdgcn_cvt_pk_fp8_f32(b.x, b.y, 0, false);
    w1 = __builtin_amdgcn_cvt_pk_fp8_f32(b.z, b.w, w1, true);

    // k-range 8jg..8jg+7: S = jg>>3, h = (jg>>2)&1, byte offset (jg&3)*8.
    *(uint2*)(dst + (jg >> 3) * 524288 + ((jg >> 2) & 1) * 262144
                  + r * 32 + (jg & 3) * 8) = make_uint2(w0, w1);

    float sq = a.x*a.x + a.y*a.y + a.z*a.z + a.w*a.w
             + b.x*b.x + b.y*b.y + b.z*b.z + b.w*b.w;
    sq += __shfl_xor(sq, 1); sq += __shfl_xor(sq, 2);
    sq += __shfl_xor(sq, 4); sq += __shfl_xor(sq, 8);
    if (jg == 0) nrm[r] = sq;
}

// 128x128 tile per block; C = A * B^T via mfma_scale 32x32x64 f8f6f4 (fp8,
// scales = 1.0): 8 MFMA per wave-tile instead of 32, halving the MFMA pipe
// (2190 -> 4686 TF measured). Operands direct-from-global as 2x dwordx4.
__global__ __launch_bounds__(256, 4) void dist_kernel(const uint8_t* __restrict__ Ak,
                                                      const uint8_t* __restrict__ Bk,
                                                      const float* __restrict__ xxg,
                                                      const float* __restrict__ yyg,
                                                      float* __restrict__ partials) {
    __shared__ float xxl[128];
    __shared__ float yyl[128];
    __shared__ float wsum[4];

    const int tid = threadIdx.x;
    const int lane = tid & 63;
    const int wid = tid >> 6;
    const int wr = wid >> 1, wc = wid & 1;      // 2x2 wave grid, each wave 64x64
    const int bx = blockIdx.x, by = blockIdx.y;

    if (tid < 128) xxl[tid] = xxg[bx * 128 + tid];
    else           yyl[tid - 128] = yyg[by * 128 + (tid - 128)];
    __syncthreads();

    const int lm = lane & 31;
    const int fh = lane >> 5;                   // k-half within a 64-k step
    const uint8_t* pa = Ak + fh * 262144 + (size_t)(bx * 128 + wr * 64 + lm) * 32;
    const uint8_t* pb = Bk + fh * 262144 + (size_t)(by * 128 + wc * 64 + lm) * 32;

    f32x16 acc[2][2] = {};
    #pragma unroll
    for (int S = 0; S < 2; ++S) {               // two K=64 steps
        v8i a0 = *(const v8i*)(pa + S * 524288);
        v8i a1 = *(const v8i*)(pa + S * 524288 + 1024);   // +32 rows
        v8i b0 = *(const v8i*)(pb + S * 524288);
        v8i b1 = *(const v8i*)(pb + S * 524288 + 1024);
        acc[0][0] = __builtin_amdgcn_mfma_scale_f32_32x32x64_f8f6f4(
                        a0, b0, acc[0][0], 0, 0, 0, 0x7F7F7F7F, 0, 0x7F7F7F7F);
        acc[0][1] = __builtin_amdgcn_mfma_scale_f32_32x32x64_f8f6f4(
                        a0, b1, acc[0][1], 0, 0, 0, 0x7F7F7F7F, 0, 0x7F7F7F7F);
        acc[1][0] = __builtin_amdgcn_mfma_scale_f32_32x32x64_f8f6f4(
                        a1, b0, acc[1][0], 0, 0, 0, 0x7F7F7F7F, 0, 0x7F7F7F7F);
        acc[1][1] = __builtin_amdgcn_mfma_scale_f32_32x32x64_f8f6f4(
                        a1, b1, acc[1][1], 0, 0, 0, 0x7F7F7F7F, 0, 0x7F7F7F7F);
    }

    // Epilogue: s += sqrt(|xx+yy-2c|)  (d2 ~ [150,400]; abs is a free input
    // modifier on v_sqrt). 2-way split accumulator chains.
    float s0 = 0.0f, s1 = 0.0f;
    #pragma unroll
    for (int tr = 0; tr < 2; ++tr) {
        float xv[16];
        #pragma unroll
        for (int r = 0; r < 16; ++r) {
            int ml = wr * 64 + tr * 32 + (r & 3) + 8 * (r >> 2) + 4 * fh;
            xv[r] = xxl[ml];
        }
        #pragma unroll
        for (int tc = 0; tc < 2; ++tc) {
            float yv = yyl[wc * 64 + tc * 32 + lm];
            #pragma unroll
            for (int r = 0; r < 16; ++r) {
                float d2 = fmaf(-2.0f, acc[tr][tc][r], xv[r] + yv);
                float d = __builtin_amdgcn_sqrtf(__builtin_fabsf(d2));
                if (r & 1) s1 += d; else s0 += d;
            }
        }
    }
    float s = s0 + s1;

    // Diagonal correction: only 64 of 4096 blocks, only waves with wr==wc.
    if (bx == by && wr == wc) {
        #pragma unroll
        for (int t = 0; t < 2; ++t) {
            #pragma unroll
            for (int r = 0; r < 16; ++r) {
                int row = (r & 3) + 8 * (r >> 2) + 4 * fh;
                if (row == lm) {
                    int idx = wr * 64 + t * 32 + row;
                    float d2 = fmaf(-2.0f, acc[t][t][r], xxl[idx] + yyl[idx]);
                    s -= 2.0f * __builtin_amdgcn_sqrtf(__builtin_fabsf(d2));
                }
            }
        }
    }

    #pragma unroll
    for (int off = 32; off > 0; off >>= 1) s += __shfl_down(s, off);
    if (lane == 0) wsum[wid] = s;
    __syncthreads();
    if (tid == 0) partials[by * 64 + bx] = wsum[0] + wsum[1] + wsum[2] + wsum[3];
}

__global__ __launch_bounds__(256) void reduce_kernel(const float* __restrict__ partials,
                                                     float* __restrict__ out) {
    __shared__ float wsum[4];
    float s = 0.0f;
    #pragma unroll
    for (int i = 0; i < 16; ++i) s += partials[threadIdx.x + i * 256];
    #pragma unroll
    for (int off = 32; off > 0; off >>= 1) s += __shfl_down(s, off);
    int lane = threadIdx.x & 63, wid = threadIdx.x >> 6;
    if (lane == 0) wsum[wid] = s;
    __syncthreads();
    if (threadIdx.x == 0)
        out[0] = (wsum[0] + wsum[1] + wsum[2] + wsum[3]) * (0.1f / 8192.0f);
}

extern "C" void kernel_launch(void* const* d_in, const int* in_sizes, int n_in,
                              void* d_out, int out_size, void* d_ws, size_t ws_size,
                              hipStream_t stream) {
    const float* output = (const float*)d_in[0];
    const float* target = (const float*)d_in[1];

    uint8_t* ws = (uint8_t*)d_ws;
    uint8_t* ak      = ws;                                      // A fp8 (1MB) + B fp8 (1MB)
    float*   xxyy    = (float*)(ws + (2u << 20));               // xx (32KB) + yy (32KB)
    float*   partial = (float*)(ws + (2u << 20) + (64u << 10)); // 4096 f32

    prep_kernel<<<dim3(512, 2), 256, 0, stream>>>(output, target, ak, xxyy);
    dist_kernel<<<dim3(64, 64), 256, 0, stream>>>(ak, ak + (1u << 20),
                                                  xxyy, xxyy + BDIM, partial);
    reduce_kernel<<<1, 256, 0, stream>>>(partial, (float*)d_out);
}